// Round 15
// baseline (1655.148 us; speedup 1.0000x reference)
//
#include <hip/hip_runtime.h>
#include <math.h>

#define K 20
#define KP1 21
#define F 32
#define NNODES 1000000

#define NP1 112896   // 5376*21
#define NP2 5376     // 256*21
#define NP3 256

// ws float offsets: 3 per-layer weight blocks of 16640 floats:
//   +0     M[a][e][h]      (8192)   Wq·Wk fold (feature part), pre-scaled by 1/4
//   +8192  C[e][h]         (256)    time-part of q folded with cos(phase), pre-scaled
//   +8448  Wv4[e4][d][c]   (4096)   canonical-packed WvT
//   +12544 P4[k4][f][c]    (3072)   Pcat = [Wo@mw1A ; mw1B]  (global/L1 at use)
//   +15616 m4[e4][d][c]    (1024)   mw2T packed
#define WBLK 16640
#define OFF_H1 49920
#define OFF_H2 (OFF_H1 + 2 * NP1 * F)
#define OFF_H3 (OFF_H2 + 2 * NP2 * F)

// LDS (dynamic), 12 waves/block (768 threads), ONE pair per wave (84-VGPR shape).
// weights in LDS: M+C+Wv4 (12544) + m4 (1024) = 13568 floats
// per-wave (1648 fl): kin [20][64] 1280 | qf 32 | qz 272 ([h*68+e]) | ob 64
#define LDS_M4   12544
#define LDS_WAVE 13568
#define WV_STRIDE 1648
#define SMEM_FLOATS (LDS_WAVE + 12 * WV_STRIDE)   // 33344 floats = 133376 B

__device__ __forceinline__ int nhash(int node, int j) {
    return (node * 101 + (j + 1) * 7919) % NNODES;   // max ~1.01e8, fits int32
}

// Cody-Waite 2-term reduction + HW cos (input revolutions). |x| <= ~1.2e4.
__device__ __forceinline__ float fast_cosf(float x) {
    const float inv2pi = 0.15915494309189535f;
    const float k = rintf(x * inv2pi);
    float r = fmaf(k, -6.28125f, x);
    r = fmaf(k, -1.9353071795864769e-3f, r);
    float rev = __builtin_amdgcn_fractf(r * inv2pi);
    return __builtin_amdgcn_cosf(rev);
}

__device__ __forceinline__ unsigned mask_bits(int na) {
    // bit j set iff (na*101 + (j+1)*7919) % 1e6 == 0  (at most one j)
    const int m0 = (na * 101) % NNODES;
    const unsigned d = (unsigned)(NNODES - m0);   // 1..1e6
    const unsigned q = d / 7919u;
    const unsigned rem = d - q * 7919u;
    return (rem == 0u && (q - 1u) < 20u) ? (1u << (q - 1u)) : 0u;
}

__global__ __launch_bounds__(256) void transform_weights(
    const float* __restrict__ Wq, const float* __restrict__ Wk,
    const float* __restrict__ Wv, const float* __restrict__ Wo,
    const float* __restrict__ mw1, const float* __restrict__ mw2,
    const float* __restrict__ phase, float* __restrict__ ws)
{
    const int l = blockIdx.x, tid = threadIdx.x;
    const float* wq = Wq + l * 4096; const float* wk = Wk + l * 4096;
    const float* wv = Wv + l * 4096; const float* wo = Wo + l * 4096;
    const float* m1 = mw1 + l * 3072; const float* m2 = mw2 + l * 1024;
    float* out = ws + l * WBLK;
    for (int i = tid; i < 8192; i += 256) {
        const int a = i >> 8, e = (i >> 2) & 63, h = i & 3;
        float s = 0.f;
        for (int t = 0; t < 16; ++t) s += wq[a * 64 + h * 16 + t] * wk[e * 64 + h * 16 + t];
        out[i] = s * 0.25f;
    }
    for (int i = tid; i < 256; i += 256) {
        const int e = i >> 2, h = i & 3;
        float s = 0.f;
        for (int a = 0; a < 32; ++a) {
            float acc = 0.f;
            for (int t = 0; t < 16; ++t) acc += wq[(32 + a) * 64 + h * 16 + t] * wk[e * 64 + h * 16 + t];
            s += cosf(phase[a]) * acc;
        }
        out[8192 + i] = s * 0.25f;
    }
    for (int i = tid; i < 4096; i += 256) {
        const int e4 = i >> 8, d = (i >> 2) & 63, c = i & 3;
        out[8448 + i] = wv[(4 * e4 + c) * 64 + d];
    }
    for (int i = tid; i < 3072; i += 256) {
        const int k4 = i >> 7, f = (i >> 2) & 31, c = i & 3;
        const int k = 4 * k4 + c;
        float v;
        if (k < 64) { v = 0.f; for (int g2 = 0; g2 < 64; ++g2) v += wo[k * 64 + g2] * m1[g2 * 32 + f]; }
        else v = m1[k * 32 + f];
        out[12544 + i] = v;
    }
    for (int i = tid; i < 1024; i += 256) {
        const int e4 = i >> 7, d = (i >> 2) & 31, c = i & 3;
        out[15616 + i] = m2[(4 * e4 + c) * 32 + d];
    }
}

template<int LEVEL>
__global__ __launch_bounds__(768) void attn_kernel(
    const int* __restrict__ src_idx, const int* __restrict__ tgt_idx,
    const float* __restrict__ cut_time, const float* __restrict__ emb,
    const float* __restrict__ freq, const float* __restrict__ phase,
    const float* __restrict__ ws_w,
    const float* __restrict__ mb1_, const float* __restrict__ mb2_,
    const float* __restrict__ h_in, float* __restrict__ h_out)
{
    constexpr int NPAIRS = (LEVEL == 1) ? NP1 : (LEVEL == 2 ? NP2 : NP3);
    constexpr int PREVN  = (LEVEL == 2) ? NP1 : NP2;
    constexpr int l = LEVEL - 1;

    extern __shared__ float smem[];

    const int tid  = threadIdx.x;
    const int w    = tid >> 6;        // 0..11
    const int lane = tid & 63;
    const int h    = lane >> 4;
    const int c3   = lane & 7;
    const int rep  = (lane >> 3) & 1;
    const int td   = lane & 31;
    const int half = lane >> 5;

    {
        const float* wsrc = ws_w + l * WBLK;
        for (int i4 = tid; i4 < 3136; i4 += 768)
            *(float4*)&smem[i4 * 4] = *(const float4*)&wsrc[i4 * 4];
        for (int i4 = tid; i4 < 256; i4 += 768)
            *(float4*)&smem[LDS_M4 + i4 * 4] = *(const float4*)&wsrc[15616 + i4 * 4];
    }
    __syncthreads();

    float* sM   = smem;               // [a*256 + e*4 + h]
    float* sC   = smem + 8192;        // [e*4 + h]
    float* sWv4 = smem + 8448;        // [e4*256 + d*4 + c]
    float* sm4  = smem + LDS_M4;      // [e4*128 + d*4 + c]
    float* wb   = smem + LDS_WAVE + w * WV_STRIDE;
    float* kin  = wb;                 // [j*64 + e]
    float* qfb  = wb + 1280;          // [32]
    float* qzb  = wb + 1312;          // [h*68 + e]
    float* obb  = wb + 1584;          // [64]

    const float* P4g = ws_w + l * WBLK + 12544;   // L1-resident merge-1 weights

    const float fr = freq[td], ph = phase[td];
    const float b1v = mb1_[l * 32 + td], b2v = mb2_[l * 32 + td];

    // score/z slice offsets (rep-swapped, bank-tiling)
    const int ofsA = c3 * 8 + rep * 4;
    const int ofsB = c3 * 8 + 4 - rep * 4;
    const int j0 = rep * 10;

    const int gstride = gridDim.x * 12;
    // prefetch state: NAMED SCALARS only (rule #20)
    float4 pf0, pf1, pf2; int na; float ta;

    const int prow  = lane >> 3, pc4 = lane & 7;
    const int prow1 = (64 + lane) >> 3, pc41 = (64 + lane) & 7;
    const int idx42 = 128 + lane;
    const int prow2 = idx42 >> 3, pc42 = idx42 & 7;

    auto PRE = [&](int i) {
        const int side = (i >= NPAIRS) ? 1 : 0;
        const int p = i - side * NPAIRS;
        int b, s2 = 0, r = 0;
        if (LEVEL == 3)      { b = p; }
        else if (LEVEL == 2) { b = p / KP1; s2 = p % KP1; }
        else                 { int qq = p / KP1; r = p % KP1; b = qq / KP1; s2 = qq % KP1; }
        const int root = side ? tgt_idx[b] : src_idx[b];
        const float ct = cut_time[b];
        if (LEVEL == 3) { na = root; ta = ct; }
        else if (LEVEL == 2) {
            na = s2 ? nhash(root, s2 - 1) : root;
            ta = s2 ? ct * ((float)s2 / 21.0f) : ct;
        } else {
            const int   n2 = s2 ? nhash(root, s2 - 1) : root;
            const float t2 = s2 ? ct * ((float)s2 / 21.0f) : ct;
            na = r ? nhash(n2, r - 1) : n2;
            ta = r ? t2 * ((float)r / 21.0f) : t2;
        }
        if (LEVEL == 1) {
            { const int node = prow ? nhash(na, prow - 1) : na;
              pf0 = *(const float4*)&emb[(size_t)node * F + pc4 * 4]; }
            { const int node = nhash(na, prow1 - 1);
              pf1 = *(const float4*)&emb[(size_t)node * F + pc41 * 4]; }
            if (idx42 < 168) {
              const int node = nhash(na, prow2 - 1);
              pf2 = *(const float4*)&emb[(size_t)node * F + pc42 * 4]; }
        } else {
            const float* base = h_in + ((size_t)side * PREVN + (size_t)p * KP1) * F;
            pf0 = *(const float4*)&base[lane * 4];
            pf1 = *(const float4*)&base[(64 + lane) * 4];
            if (idx42 < 168) pf2 = *(const float4*)&base[idx42 * 4];
        }
    };

    int g = blockIdx.x * 12 + w;
    if (g < 2 * NPAIRS) PRE(g);

    for (; g < 2 * NPAIRS; g += gstride) {
        const int gs = g;
        const int cna = na;
        const float cta = ta;

        // ---- fill LDS from prefetch scalars
        { if (prow == 0) *(float4*)&qfb[pc4 * 4] = pf0;
          else           *(float4*)&kin[(prow - 1) * 64 + pc4 * 4] = pf0; }
        *(float4*)&kin[(prow1 - 1) * 64 + pc41 * 4] = pf1;
        if (idx42 < 168) *(float4*)&kin[(prow2 - 1) * 64 + pc42 * 4] = pf2;

        // ---- time encodings (fast Cody-Waite cos)
        #pragma unroll
        for (int it = 0; it < 10; ++it) {
            const int j = it * 2 + half;
            const float ngh_t = cta * ((float)(j + 1) / 21.0f);
            const float delta = cta - ngh_t;
            kin[j * 64 + 32 + td] = fast_cosf(delta * fr + ph);
        }
        // ---- mask bits via magic division
        const unsigned mbits = mask_bits(cna);

        if (g + gstride < 2 * NPAIRS) PRE(g + gstride);

        // ---- QK phase: lane = e (M,C pre-scaled by 1/sqrt(16))
        float4 acc = *(const float4*)&sC[lane * 4];
        #pragma unroll
        for (int a4 = 0; a4 < 8; ++a4) {
            const float4 f4 = *(float4*)&qfb[a4 * 4];
            const float4 m0 = *(const float4*)&sM[(a4 * 4 + 0) * 256 + lane * 4];
            const float4 m1v = *(const float4*)&sM[(a4 * 4 + 1) * 256 + lane * 4];
            const float4 m2v = *(const float4*)&sM[(a4 * 4 + 2) * 256 + lane * 4];
            const float4 m3 = *(const float4*)&sM[(a4 * 4 + 3) * 256 + lane * 4];
            acc.x += f4.x * m0.x + f4.y * m1v.x + f4.z * m2v.x + f4.w * m3.x;
            acc.y += f4.x * m0.y + f4.y * m1v.y + f4.z * m2v.y + f4.w * m3.y;
            acc.z += f4.x * m0.z + f4.y * m1v.z + f4.z * m2v.z + f4.w * m3.z;
            acc.w += f4.x * m0.w + f4.y * m1v.w + f4.z * m2v.w + f4.w * m3.w;
        }
        qzb[0 * 68 + lane] = acc.x; qzb[1 * 68 + lane] = acc.y;
        qzb[2 * 68 + lane] = acc.z; qzb[3 * 68 + lane] = acc.w;

        // ---- FUSED single-pass score+softmax+z (no-max exp; mask -> exp = 0)
        {
            const float4 qkA = *(float4*)&qzb[h * 68 + ofsA];
            const float4 qkB = *(float4*)&qzb[h * 68 + ofsB];
            float4 zA = {0, 0, 0, 0}, zB = {0, 0, 0, 0};
            float sum = 0.f;
            #pragma unroll
            for (int t = 0; t < 10; ++t) {
                const float4 kA = *(float4*)&kin[(j0 + t) * 64 + ofsA];
                const float4 kB = *(float4*)&kin[(j0 + t) * 64 + ofsB];
                float s = qkA.x * kA.x + qkA.y * kA.y + qkA.z * kA.z + qkA.w * kA.w
                        + qkB.x * kB.x + qkB.y * kB.y + qkB.z * kB.z + qkB.w * kB.w;
                s += __shfl_xor(s, 1, 16);
                s += __shfl_xor(s, 2, 16);
                s += __shfl_xor(s, 4, 16);
                if ((mbits >> (j0 + t)) & 1) s = -1e9f;
                const float p = __expf(s);
                sum += p;
                zA.x += p * kA.x; zA.y += p * kA.y; zA.z += p * kA.z; zA.w += p * kA.w;
                zB.x += p * kB.x; zB.y += p * kB.y; zB.z += p * kB.z; zB.w += p * kB.w;
            }
            sum += __shfl_xor(sum, 8, 16);
            const float inv = 1.0f / sum;
            float4 fA, fB;
            fA.x = zA.x + __shfl_xor(zB.x, 8, 16); fA.y = zA.y + __shfl_xor(zB.y, 8, 16);
            fA.z = zA.z + __shfl_xor(zB.z, 8, 16); fA.w = zA.w + __shfl_xor(zB.w, 8, 16);
            fB.x = zB.x + __shfl_xor(zA.x, 8, 16); fB.y = zB.y + __shfl_xor(zA.y, 8, 16);
            fB.z = zB.z + __shfl_xor(zA.z, 8, 16); fB.w = zB.w + __shfl_xor(zA.w, 8, 16);
            fA.x *= inv; fA.y *= inv; fA.z *= inv; fA.w *= inv;
            fB.x *= inv; fB.y *= inv; fB.z *= inv; fB.w *= inv;
            if (rep == 0) {
                *(float4*)&qzb[h * 68 + ofsA] = fA;      // ofsA = c3*8
                *(float4*)&qzb[h * 68 + ofsB] = fB;      // ofsB = c3*8+4
            }
        }

        // ---- OD: lane = d
        float od = 0.f;
        #pragma unroll
        for (int e4 = 0; e4 < 16; ++e4) {
            const float4 z  = *(float4*)&qzb[h * 68 + e4 * 4];
            const float4 wv = *(float4*)&sWv4[e4 * 256 + lane * 4];
            od += z.x * wv.x + z.y * wv.y + z.z * wv.z + z.w * wv.w;
        }
        obb[lane] = od;

        // ---- merge1 via Pcat (global/L1)
        float hv = 0.f;
        #pragma unroll
        for (int e4 = 0; e4 < 12; ++e4) {
            float4 x;
            if (half == 0) x = *(float4*)&obb[e4 * 4];
            else x = (e4 < 4) ? *(float4*)&obb[48 + e4 * 4]
                              : *(float4*)&qfb[(e4 - 4) * 4];
            const float4 w4 = *(const float4*)&P4g[(half * 12 + e4) * 128 + td * 4];
            hv += x.x * w4.x + x.y * w4.y + x.z * w4.z + x.w * w4.w;
        }
        hv += __shfl_xor(hv, 32);
        hv = fmaxf(hv + b1v, 0.0f);
        if (lane < 32) obb[td] = hv;

        // ---- merge2 (LDS) + store
        float y = 0.f;
        #pragma unroll
        for (int e4 = 0; e4 < 4; ++e4) {
            const float4 x  = *(float4*)&obb[half * 16 + e4 * 4];
            const float4 w4 = *(float4*)&sm4[(half * 4 + e4) * 128 + td * 4];
            y += x.x * w4.x + x.y * w4.y + x.z * w4.z + x.w * w4.w;
        }
        y += __shfl_xor(y, 32);
        if (lane < 32) {
            const int side = (gs >= NPAIRS) ? 1 : 0;
            const int p = gs - side * NPAIRS;
            h_out[((size_t)side * NPAIRS + p) * F + td] = y + b2v;
        }
    }
}

__global__ __launch_bounds__(256) void final_kernel(
    const float* __restrict__ h3,
    const float* __restrict__ aw1, const float* __restrict__ ab1,
    const float* __restrict__ aw2, const float* __restrict__ ab2,
    float* __restrict__ out)
{
    const int bidx = threadIdx.x;   // 256 threads, 1 block
    float x[64];
    #pragma unroll
    for (int e = 0; e < 32; ++e) {
        x[e]      = h3[(size_t)bidx * 32 + e];
        x[32 + e] = h3[((size_t)NP3 + bidx) * 32 + e];
    }
    float acc = ab2[0];
    for (int f = 0; f < 32; ++f) {
        float hv = ab1[f];
        #pragma unroll
        for (int e = 0; e < 64; ++e) hv += x[e] * aw1[e * 32 + f];
        acc += fmaxf(hv, 0.0f) * aw2[f];
    }
    out[bidx] = acc;
}

extern "C" void kernel_launch(void* const* d_in, const int* in_sizes, int n_in,
                              void* d_out, int out_size, void* d_ws, size_t ws_size,
                              hipStream_t stream)
{
    const int*   src_idx = (const int*)d_in[0];
    const int*   tgt_idx = (const int*)d_in[1];
    const float* cut     = (const float*)d_in[2];
    const float* emb   = (const float*)d_in[4];
    const float* freq  = (const float*)d_in[5];
    const float* phase = (const float*)d_in[6];
    const float* Wq    = (const float*)d_in[7];
    const float* Wk    = (const float*)d_in[8];
    const float* Wv    = (const float*)d_in[9];
    const float* Wo    = (const float*)d_in[10];
    const float* mw1   = (const float*)d_in[11];
    const float* mb1   = (const float*)d_in[12];
    const float* mw2   = (const float*)d_in[13];
    const float* mb2   = (const float*)d_in[14];
    const float* aw1   = (const float*)d_in[15];
    const float* ab1   = (const float*)d_in[16];
    const float* aw2   = (const float*)d_in[17];
    const float* ab2   = (const float*)d_in[18];

    float* ws = (float*)d_ws;
    float* h1 = ws + OFF_H1;
    float* h2 = ws + OFF_H2;
    float* h3 = ws + OFF_H3;

    const size_t smem_bytes = SMEM_FLOATS * sizeof(float);
    hipFuncSetAttribute((const void*)attn_kernel<1>, hipFuncAttributeMaxDynamicSharedMemorySize, (int)smem_bytes);
    hipFuncSetAttribute((const void*)attn_kernel<2>, hipFuncAttributeMaxDynamicSharedMemorySize, (int)smem_bytes);
    hipFuncSetAttribute((const void*)attn_kernel<3>, hipFuncAttributeMaxDynamicSharedMemorySize, (int)smem_bytes);

    transform_weights<<<dim3(3), dim3(256), 0, stream>>>(Wq, Wk, Wv, Wo, mw1, mw2, phase, ws);
    attn_kernel<1><<<dim3(256), dim3(768), smem_bytes, stream>>>(
        src_idx, tgt_idx, cut, emb, freq, phase, ws, mb1, mb2, (const float*)nullptr, h1);
    attn_kernel<2><<<dim3(256), dim3(768), smem_bytes, stream>>>(
        src_idx, tgt_idx, cut, emb, freq, phase, ws, mb1, mb2, h1, h2);
    attn_kernel<3><<<dim3(43), dim3(768), smem_bytes, stream>>>(
        src_idx, tgt_idx, cut, emb, freq, phase, ws, mb1, mb2, h2, h3);
    final_kernel<<<dim3(1), dim3(256), 0, stream>>>(h3, aw1, ab1, aw2, ab2, (float*)d_out);
}

// Round 16
// 641.431 us; speedup vs baseline: 2.5804x; 2.5804x over previous
//
#include <hip/hip_runtime.h>
#include <math.h>

#define K 20
#define KP1 21
#define F 32
#define NNODES 1000000

#define NP1 112896   // 5376*21
#define NP2 5376     // 256*21
#define NP3 256

// ws float offsets: 3 per-layer weight blocks of 16640 floats:
//   +0     M[a][e][h]      (8192)   Wq·Wk fold (feature part)
//   +8192  C[e][h]         (256)    time-part of q folded with cos(phase)
//   +8448  Wv4[e4][d][c]   (4096)   canonical-packed WvT
//   +12544 P4[k4][f][c]    (3072)   Pcat = [Wo@mw1A ; mw1B]  (global/L1 at use)
//   +15616 m4[e4][d][c]    (1024)   mw2T packed
#define WBLK 16640
#define OFF_H1 49920
#define OFF_H2 (OFF_H1 + 2 * NP1 * F)
#define OFF_H3 (OFF_H2 + 2 * NP2 * F)

// LDS float offsets (dynamic smem), 8 waves/block (512 threads), NB=2 pairs/wave
#define LDS_M4   12544
#define LDS_WAVE 13568
#define WV_STRIDE 3296
#define SMEM_FLOATS (LDS_WAVE + 8 * WV_STRIDE)   // 39936 floats = 159744 B

__device__ __forceinline__ int nhash(int node, int j) {
    return (node * 101 + (j + 1) * 7919) % NNODES;   // max ~1.01e8, fits int32
}

__global__ __launch_bounds__(256) void transform_weights(
    const float* __restrict__ Wq, const float* __restrict__ Wk,
    const float* __restrict__ Wv, const float* __restrict__ Wo,
    const float* __restrict__ mw1, const float* __restrict__ mw2,
    const float* __restrict__ phase, float* __restrict__ ws)
{
    const int l = blockIdx.x, tid = threadIdx.x;
    const float* wq = Wq + l * 4096; const float* wk = Wk + l * 4096;
    const float* wv = Wv + l * 4096; const float* wo = Wo + l * 4096;
    const float* m1 = mw1 + l * 3072; const float* m2 = mw2 + l * 1024;
    float* out = ws + l * WBLK;
    for (int i = tid; i < 8192; i += 256) {
        const int a = i >> 8, e = (i >> 2) & 63, h = i & 3;
        float s = 0.f;
        for (int t = 0; t < 16; ++t) s += wq[a * 64 + h * 16 + t] * wk[e * 64 + h * 16 + t];
        out[i] = s;
    }
    for (int i = tid; i < 256; i += 256) {
        const int e = i >> 2, h = i & 3;
        float s = 0.f;
        for (int a = 0; a < 32; ++a) {
            float acc = 0.f;
            for (int t = 0; t < 16; ++t) acc += wq[(32 + a) * 64 + h * 16 + t] * wk[e * 64 + h * 16 + t];
            s += cosf(phase[a]) * acc;
        }
        out[8192 + i] = s;
    }
    for (int i = tid; i < 4096; i += 256) {
        const int e4 = i >> 8, d = (i >> 2) & 63, c = i & 3;
        out[8448 + i] = wv[(4 * e4 + c) * 64 + d];
    }
    for (int i = tid; i < 3072; i += 256) {
        const int k4 = i >> 7, f = (i >> 2) & 31, c = i & 3;
        const int k = 4 * k4 + c;
        float v;
        if (k < 64) { v = 0.f; for (int g2 = 0; g2 < 64; ++g2) v += wo[k * 64 + g2] * m1[g2 * 32 + f]; }
        else v = m1[k * 32 + f];
        out[12544 + i] = v;
    }
    for (int i = tid; i < 1024; i += 256) {
        const int e4 = i >> 7, d = (i >> 2) & 31, c = i & 3;
        out[15616 + i] = m2[(4 * e4 + c) * 32 + d];
    }
}

template<int LEVEL>
__global__ __launch_bounds__(512, 1) void attn_kernel(
    const int* __restrict__ src_idx, const int* __restrict__ tgt_idx,
    const float* __restrict__ cut_time, const float* __restrict__ emb,
    const float* __restrict__ freq, const float* __restrict__ phase,
    const float* __restrict__ ws_w,
    const float* __restrict__ mb1_, const float* __restrict__ mb2_,
    const float* __restrict__ h_in, float* __restrict__ h_out)
{
    constexpr int NPAIRS = (LEVEL == 1) ? NP1 : (LEVEL == 2 ? NP2 : NP3);
    constexpr int PREVN  = (LEVEL == 2) ? NP1 : NP2;
    constexpr int l = LEVEL - 1;

    extern __shared__ float smem[];

    const int tid  = threadIdx.x;
    const int w    = tid >> 6;        // 0..7
    const int lane = tid & 63;
    const int h    = lane >> 4;
    const int c3   = lane & 7;
    const int rep  = (lane >> 3) & 1;
    const int td   = lane & 31;
    const int half = lane >> 5;

    {
        const float* wsrc = ws_w + l * WBLK;
        for (int i4 = tid; i4 < 3136; i4 += 512)
            *(float4*)&smem[i4 * 4] = *(const float4*)&wsrc[i4 * 4];
        for (int i4 = tid; i4 < 256; i4 += 512)
            *(float4*)&smem[LDS_M4 + i4 * 4] = *(const float4*)&wsrc[15616 + i4 * 4];
    }
    __syncthreads();

    float* sM   = smem;               // [a*256 + e*4 + h]
    float* sC   = smem + 8192;        // [e*4 + h]
    float* sWv4 = smem + 8448;        // [e4*256 + d*4 + c]
    float* sm4  = smem + LDS_M4;      // [e4*128 + d*4 + c]
    float* wb   = smem + LDS_WAVE + w * WV_STRIDE;
    float* kin0 = wb;                 // [j*64 + e]  (side 0)
    float* kin1 = wb + 1280;          // (side 1)
    float* qf0  = wb + 2560;          // [32]
    float* qf1  = wb + 2592;
    float* qz0  = wb + 2624;          // [h*68 + e]
    float* qz1  = wb + 2896;
    float* ob0  = wb + 3168;          // [64]
    float* ob1  = wb + 3232;

    const float* P4g = ws_w + l * WBLK + 12544;   // L1-resident merge-1 weights

    const float fr = freq[td], ph = phase[td];
    const float b1v = mb1_[l * 32 + td], b2v = mb2_[l * 32 + td];

    const int gstride = gridDim.x * 8;
    // prefetch state: NAMED SCALARS (arrays here go to scratch — rule #20)
    float4 pf00, pf01, pf02, pf10, pf11, pf12;
    int na0, na1; float ta;

    const int prow  = lane >> 3, pc4 = lane & 7;          // for pf*0
    const int prow1 = (64 + lane) >> 3, pc41 = (64 + lane) & 7;  // for pf*1
    const int idx42 = 128 + lane;                          // for pf*2
    const int prow2 = idx42 >> 3, pc42 = idx42 & 7;

    auto PRE = [&](int p) {
        int b, s2 = 0, r = 0;
        if (LEVEL == 3)      { b = p; }
        else if (LEVEL == 2) { b = p / KP1; s2 = p % KP1; }
        else                 { int qq = p / KP1; r = p % KP1; b = qq / KP1; s2 = qq % KP1; }
        const float ct = cut_time[b];
        const int root0 = src_idx[b];
        const int root1 = tgt_idx[b];
        if (LEVEL == 3) { ta = ct; }
        else if (LEVEL == 2) { ta = s2 ? ct * ((float)s2 / 21.0f) : ct; }
        else {
            const float t2 = s2 ? ct * ((float)s2 / 21.0f) : ct;
            ta = r ? t2 * ((float)r / 21.0f) : t2;
        }
        int nA0, nA1;
        if (LEVEL == 3) { nA0 = root0; nA1 = root1; }
        else if (LEVEL == 2) {
            nA0 = s2 ? nhash(root0, s2 - 1) : root0;
            nA1 = s2 ? nhash(root1, s2 - 1) : root1;
        } else {
            const int n20 = s2 ? nhash(root0, s2 - 1) : root0;
            const int n21 = s2 ? nhash(root1, s2 - 1) : root1;
            nA0 = r ? nhash(n20, r - 1) : n20;
            nA1 = r ? nhash(n21, r - 1) : n21;
        }
        na0 = nA0; na1 = nA1;
        if (LEVEL == 1) {
            { const int node = prow ? nhash(nA0, prow - 1) : nA0;
              pf00 = *(const float4*)&emb[(size_t)node * F + pc4 * 4]; }
            { const int node = nhash(nA0, prow1 - 1);
              pf01 = *(const float4*)&emb[(size_t)node * F + pc41 * 4]; }
            if (idx42 < 168) {
              const int node = nhash(nA0, prow2 - 1);
              pf02 = *(const float4*)&emb[(size_t)node * F + pc42 * 4]; }
            { const int node = prow ? nhash(nA1, prow - 1) : nA1;
              pf10 = *(const float4*)&emb[(size_t)node * F + pc4 * 4]; }
            { const int node = nhash(nA1, prow1 - 1);
              pf11 = *(const float4*)&emb[(size_t)node * F + pc41 * 4]; }
            if (idx42 < 168) {
              const int node = nhash(nA1, prow2 - 1);
              pf12 = *(const float4*)&emb[(size_t)node * F + pc42 * 4]; }
        } else {
            const float* base0 = h_in + ((size_t)p * KP1) * F;
            const float* base1 = h_in + ((size_t)PREVN + (size_t)p * KP1) * F;
            pf00 = *(const float4*)&base0[lane * 4];
            pf01 = *(const float4*)&base0[(64 + lane) * 4];
            if (idx42 < 168) pf02 = *(const float4*)&base0[idx42 * 4];
            pf10 = *(const float4*)&base1[lane * 4];
            pf11 = *(const float4*)&base1[(64 + lane) * 4];
            if (idx42 < 168) pf12 = *(const float4*)&base1[idx42 * 4];
        }
    };

    int g = blockIdx.x * 8 + w;
    if (g < NPAIRS) PRE(g);

    for (; g < NPAIRS; g += gstride) {
        const int gs = g;
        const int cna0 = na0, cna1 = na1;
        const float cta = ta;

        // ---- fill LDS from prefetch scalars (both sides)
        { if (prow == 0) *(float4*)&qf0[pc4 * 4] = pf00;
          else           *(float4*)&kin0[(prow - 1) * 64 + pc4 * 4] = pf00; }
        *(float4*)&kin0[(prow1 - 1) * 64 + pc41 * 4] = pf01;
        if (idx42 < 168) *(float4*)&kin0[(prow2 - 1) * 64 + pc42 * 4] = pf02;
        { if (prow == 0) *(float4*)&qf1[pc4 * 4] = pf10;
          else           *(float4*)&kin1[(prow - 1) * 64 + pc4 * 4] = pf10; }
        *(float4*)&kin1[(prow1 - 1) * 64 + pc41 * 4] = pf11;
        if (idx42 < 168) *(float4*)&kin1[(prow2 - 1) * 64 + pc42 * 4] = pf12;

        // ---- time encodings: once per couple (shared tA), written to both
        #pragma unroll
        for (int it = 0; it < 10; ++it) {
            const int j = it * 2 + half;
            const float ngh_t = cta * ((float)(j + 1) / 21.0f);
            const float delta = cta - ngh_t;
            const float cv = cosf(delta * fr + ph);
            kin0[j * 64 + 32 + td] = cv;
            kin1[j * 64 + 32 + td] = cv;
        }
        // ---- mask bits per side (incremental mod), named scalars
        unsigned mb0bits, mb1bits;
        { int m = (cna0 * 101 + 7919) % NNODES; unsigned bits = 0;
          #pragma unroll
          for (int j = 0; j < K; ++j) { if (m == 0) bits |= (1u << j); m += 7919; if (m >= NNODES) m -= NNODES; }
          mb0bits = bits; }
        { int m = (cna1 * 101 + 7919) % NNODES; unsigned bits = 0;
          #pragma unroll
          for (int j = 0; j < K; ++j) { if (m == 0) bits |= (1u << j); m += 7919; if (m >= NNODES) m -= NNODES; }
          mb1bits = bits; }

        if (g + gstride < NPAIRS) PRE(g + gstride);

        // ---- QK phase (batched): lane = e
        float4 acc0 = *(const float4*)&sC[lane * 4];
        float4 acc1 = acc0;
        #pragma unroll
        for (int a4 = 0; a4 < 8; ++a4) {
            const float4 f0 = *(float4*)&qf0[a4 * 4];
            const float4 f1 = *(float4*)&qf1[a4 * 4];
            const float4 m0 = *(const float4*)&sM[(a4 * 4 + 0) * 256 + lane * 4];
            const float4 m1v = *(const float4*)&sM[(a4 * 4 + 1) * 256 + lane * 4];
            const float4 m2v = *(const float4*)&sM[(a4 * 4 + 2) * 256 + lane * 4];
            const float4 m3 = *(const float4*)&sM[(a4 * 4 + 3) * 256 + lane * 4];
            acc0.x += f0.x * m0.x + f0.y * m1v.x + f0.z * m2v.x + f0.w * m3.x;
            acc0.y += f0.x * m0.y + f0.y * m1v.y + f0.z * m2v.y + f0.w * m3.y;
            acc0.z += f0.x * m0.z + f0.y * m1v.z + f0.z * m2v.z + f0.w * m3.z;
            acc0.w += f0.x * m0.w + f0.y * m1v.w + f0.z * m2v.w + f0.w * m3.w;
            acc1.x += f1.x * m0.x + f1.y * m1v.x + f1.z * m2v.x + f1.w * m3.x;
            acc1.y += f1.x * m0.y + f1.y * m1v.y + f1.z * m2v.y + f1.w * m3.y;
            acc1.z += f1.x * m0.z + f1.y * m1v.z + f1.z * m2v.z + f1.w * m3.z;
            acc1.w += f1.x * m0.w + f1.y * m1v.w + f1.z * m2v.w + f1.w * m3.w;
        }
        qz0[0 * 68 + lane] = acc0.x; qz0[1 * 68 + lane] = acc0.y;
        qz0[2 * 68 + lane] = acc0.z; qz0[3 * 68 + lane] = acc0.w;
        qz1[0 * 68 + lane] = acc1.x; qz1[1 * 68 + lane] = acc1.y;
        qz1[2 * 68 + lane] = acc1.z; qz1[3 * 68 + lane] = acc1.w;

        // ---- per-side: scores -> softmax -> z  (rep-swapped slices)
        const int ofsA = c3 * 8 + rep * 4;
        const int ofsB = c3 * 8 + 4 - rep * 4;
        const int j0 = rep * 10;
        #pragma unroll
        for (int q = 0; q < 2; ++q) {
            float* kin = q ? kin1 : kin0;
            float* qzb = q ? qz1 : qz0;
            const unsigned mbq = q ? mb1bits : mb0bits;
            const float4 qkA = *(float4*)&qzb[h * 68 + ofsA];
            const float4 qkB = *(float4*)&qzb[h * 68 + ofsB];
            float sc[10];
            #pragma unroll
            for (int t = 0; t < 10; ++t) {
                const float4 kA = *(float4*)&kin[(j0 + t) * 64 + ofsA];
                const float4 kB = *(float4*)&kin[(j0 + t) * 64 + ofsB];
                sc[t] = qkA.x * kA.x + qkA.y * kA.y + qkA.z * kA.z + qkA.w * kA.w
                      + qkB.x * kB.x + qkB.y * kB.y + qkB.z * kB.z + qkB.w * kB.w;
            }
            #pragma unroll
            for (int off = 1; off < 8; off <<= 1) {
                #pragma unroll
                for (int t = 0; t < 10; ++t) sc[t] += __shfl_xor(sc[t], off, 8);
            }
            #pragma unroll
            for (int t = 0; t < 10; ++t) {
                float s = sc[t] * 0.25f;                  // 1/sqrt(16)
                if ((mbq >> (j0 + t)) & 1) s = -1e9f;
                sc[t] = s;
            }
            float mx = sc[0];
            #pragma unroll
            for (int t = 1; t < 10; ++t) mx = fmaxf(mx, sc[t]);
            mx = fmaxf(mx, __shfl_xor(mx, 8, 16));
            float sum = 0.f;
            #pragma unroll
            for (int t = 0; t < 10; ++t) { sc[t] = __expf(sc[t] - mx); sum += sc[t]; }
            sum += __shfl_xor(sum, 8, 16);
            const float inv = 1.0f / sum;
            float4 zA = {0, 0, 0, 0}, zB = {0, 0, 0, 0};
            #pragma unroll
            for (int t = 0; t < 10; ++t) {
                const float4 kA = *(float4*)&kin[(j0 + t) * 64 + ofsA];
                const float4 kB = *(float4*)&kin[(j0 + t) * 64 + ofsB];
                zA.x += sc[t] * kA.x; zA.y += sc[t] * kA.y; zA.z += sc[t] * kA.z; zA.w += sc[t] * kA.w;
                zB.x += sc[t] * kB.x; zB.y += sc[t] * kB.y; zB.z += sc[t] * kB.z; zB.w += sc[t] * kB.w;
            }
            float4 fA, fB;
            fA.x = zA.x + __shfl_xor(zB.x, 8, 16); fA.y = zA.y + __shfl_xor(zB.y, 8, 16);
            fA.z = zA.z + __shfl_xor(zB.z, 8, 16); fA.w = zA.w + __shfl_xor(zB.w, 8, 16);
            fB.x = zB.x + __shfl_xor(zA.x, 8, 16); fB.y = zB.y + __shfl_xor(zA.y, 8, 16);
            fB.z = zB.z + __shfl_xor(zA.z, 8, 16); fB.w = zB.w + __shfl_xor(zA.w, 8, 16);
            fA.x *= inv; fA.y *= inv; fA.z *= inv; fA.w *= inv;
            fB.x *= inv; fB.y *= inv; fB.z *= inv; fB.w *= inv;
            if (rep == 0) {
                *(float4*)&qzb[h * 68 + ofsA] = fA;      // ofsA = c3*8
                *(float4*)&qzb[h * 68 + ofsB] = fB;      // ofsB = c3*8+4
            }
        }

        // ---- OD (batched): lane = d
        float od0 = 0.f, od1 = 0.f;
        #pragma unroll
        for (int e4 = 0; e4 < 16; ++e4) {
            const float4 wv = *(float4*)&sWv4[e4 * 256 + lane * 4];
            const float4 z0 = *(float4*)&qz0[h * 68 + e4 * 4];
            const float4 z1 = *(float4*)&qz1[h * 68 + e4 * 4];
            od0 += z0.x * wv.x + z0.y * wv.y + z0.z * wv.z + z0.w * wv.w;
            od1 += z1.x * wv.x + z1.y * wv.y + z1.z * wv.z + z1.w * wv.w;
        }
        ob0[lane] = od0;
        ob1[lane] = od1;

        // ---- merge1 via Pcat (global/L1, batched)
        float hv0 = 0.f, hv1 = 0.f;
        #pragma unroll
        for (int e4 = 0; e4 < 12; ++e4) {
            float4 x0, x1;
            if (half == 0) { x0 = *(float4*)&ob0[e4 * 4]; x1 = *(float4*)&ob1[e4 * 4]; }
            else {
                x0 = (e4 < 4) ? *(float4*)&ob0[48 + e4 * 4] : *(float4*)&qf0[(e4 - 4) * 4];
                x1 = (e4 < 4) ? *(float4*)&ob1[48 + e4 * 4] : *(float4*)&qf1[(e4 - 4) * 4];
            }
            const float4 w4 = *(const float4*)&P4g[(half * 12 + e4) * 128 + td * 4];
            hv0 += x0.x * w4.x + x0.y * w4.y + x0.z * w4.z + x0.w * w4.w;
            hv1 += x1.x * w4.x + x1.y * w4.y + x1.z * w4.z + x1.w * w4.w;
        }
        hv0 += __shfl_xor(hv0, 32);
        hv1 += __shfl_xor(hv1, 32);
        hv0 = fmaxf(hv0 + b1v, 0.0f);
        hv1 = fmaxf(hv1 + b1v, 0.0f);
        if (lane < 32) { ob0[td] = hv0; ob1[td] = hv1; }

        // ---- merge2 (LDS, batched) + store
        float y0 = 0.f, y1 = 0.f;
        #pragma unroll
        for (int e4 = 0; e4 < 4; ++e4) {
            const float4 w4 = *(float4*)&sm4[(half * 4 + e4) * 128 + td * 4];
            const float4 x0 = *(float4*)&ob0[half * 16 + e4 * 4];
            const float4 x1 = *(float4*)&ob1[half * 16 + e4 * 4];
            y0 += x0.x * w4.x + x0.y * w4.y + x0.z * w4.z + x0.w * w4.w;
            y1 += x1.x * w4.x + x1.y * w4.y + x1.z * w4.z + x1.w * w4.w;
        }
        y0 += __shfl_xor(y0, 32);
        y1 += __shfl_xor(y1, 32);
        if (lane < 32) {
            h_out[((size_t)0 * NPAIRS + gs) * F + td] = y0 + b2v;
            h_out[((size_t)1 * NPAIRS + gs) * F + td] = y1 + b2v;
        }
    }
}

__global__ __launch_bounds__(256) void final_kernel(
    const float* __restrict__ h3,
    const float* __restrict__ aw1, const float* __restrict__ ab1,
    const float* __restrict__ aw2, const float* __restrict__ ab2,
    float* __restrict__ out)
{
    const int bidx = threadIdx.x;   // 256 threads, 1 block
    float x[64];
    #pragma unroll
    for (int e = 0; e < 32; ++e) {
        x[e]      = h3[(size_t)bidx * 32 + e];
        x[32 + e] = h3[((size_t)NP3 + bidx) * 32 + e];
    }
    float acc = ab2[0];
    for (int f = 0; f < 32; ++f) {
        float hv = ab1[f];
        #pragma unroll
        for (int e = 0; e < 64; ++e) hv += x[e] * aw1[e * 32 + f];
        acc += fmaxf(hv, 0.0f) * aw2[f];
    }
    out[bidx] = acc;
}

extern "C" void kernel_launch(void* const* d_in, const int* in_sizes, int n_in,
                              void* d_out, int out_size, void* d_ws, size_t ws_size,
                              hipStream_t stream)
{
    const int*   src_idx = (const int*)d_in[0];
    const int*   tgt_idx = (const int*)d_in[1];
    const float* cut     = (const float*)d_in[2];
    const float* emb   = (const float*)d_in[4];
    const float* freq  = (const float*)d_in[5];
    const float* phase = (const float*)d_in[6];
    const float* Wq    = (const float*)d_in[7];
    const float* Wk    = (const float*)d_in[8];
    const float* Wv    = (const float*)d_in[9];
    const float* Wo    = (const float*)d_in[10];
    const float* mw1   = (const float*)d_in[11];
    const float* mb1   = (const float*)d_in[12];
    const float* mw2   = (const float*)d_in[13];
    const float* mb2   = (const float*)d_in[14];
    const float* aw1   = (const float*)d_in[15];
    const float* ab1   = (const float*)d_in[16];
    const float* aw2   = (const float*)d_in[17];
    const float* ab2   = (const float*)d_in[18];

    float* ws = (float*)d_ws;
    float* h1 = ws + OFF_H1;
    float* h2 = ws + OFF_H2;
    float* h3 = ws + OFF_H3;

    const size_t smem_bytes = SMEM_FLOATS * sizeof(float);
    hipFuncSetAttribute((const void*)attn_kernel<1>, hipFuncAttributeMaxDynamicSharedMemorySize, (int)smem_bytes);
    hipFuncSetAttribute((const void*)attn_kernel<2>, hipFuncAttributeMaxDynamicSharedMemorySize, (int)smem_bytes);
    hipFuncSetAttribute((const void*)attn_kernel<3>, hipFuncAttributeMaxDynamicSharedMemorySize, (int)smem_bytes);

    transform_weights<<<dim3(3), dim3(256), 0, stream>>>(Wq, Wk, Wv, Wo, mw1, mw2, phase, ws);
    attn_kernel<1><<<dim3(256), dim3(512), smem_bytes, stream>>>(
        src_idx, tgt_idx, cut, emb, freq, phase, ws, mb1, mb2, (const float*)nullptr, h1);
    attn_kernel<2><<<dim3(256), dim3(512), smem_bytes, stream>>>(
        src_idx, tgt_idx, cut, emb, freq, phase, ws, mb1, mb2, h1, h2);
    attn_kernel<3><<<dim3(32), dim3(512), smem_bytes, stream>>>(
        src_idx, tgt_idx, cut, emb, freq, phase, ws, mb1, mb2, h2, h3);
    final_kernel<<<dim3(1), dim3(256), 0, stream>>>(h3, aw1, ab1, aw2, ab2, (float*)d_out);
}